// Round 13
// baseline (3821.209 us; speedup 1.0000x reference)
//
#include <hip/hip_runtime.h>

// VanillaRNNLayer: B=32, T=2048, I=512, H=512 — ALL FP32.
//   phase 1: xp = x @ Wx^T + bx + bh   -> fp32 into d_out (consumed in place)
//   phase 2: h_t = tanh(xp_t + Wh h_{t-1}), 8 blocks/chain, Wh slice in regs.
// R12 lesson: partial-exchange = 8x IC volume (WRITE 2GB) — exchange must
// stay at h-granularity. R13 = R7 champion structure with two changes:
//   1. staggered 3-deep poll: issue relaxed-agent loads interleaved with
//      the FMA chunks (pinned by memory clobbers), rotate-check+reissue
//      after B-mid -> detect cadence ~lat/3 and sampling starts during FMA.
//   2. pacc transposed to pq[32][68]: finisher reduce reads bank-conflict
//      free (R7's [64][36] b128 reads were 8-way aliased).
// Exchange protocol (slots, tags, publish order) is byte-identical to R7.

constexpr int Bb = 32, Tt = 2048, Ii = 512, Hh = 512;
constexpr int NP = 8;            // parts (blocks) per chain
constexpr int RP = Hh / NP;      // 64 rows per part

static __device__ __forceinline__ float fast_tanh(float x) {
    float ax = fabsf(x);
    float e = __expf(-2.0f * ax);            // in (0,1], no overflow
    float r = (1.0f - e) / (1.0f + e);
    return copysignf(r, x);
}

// ---------------- Phase 1: xp GEMM, 128x128 tile, 8x8/thread ----------------
// Measured ~0.34 ms ~= fp32 vector roofline for 34.4 GFLOP — done.
__global__ __launch_bounds__(256, 2)
void xproj_gemm(const float* __restrict__ x, const float* __restrict__ Wx,
                const float* __restrict__ bx, const float* __restrict__ bh,
                float* __restrict__ xp)
{
    constexpr int BM = 128, BK = 16, LDT = BM + 4;   // [k][m] transposed tiles
    __shared__ float As[BK][LDT];
    __shared__ float Bs[BK][LDT];

    const int tid = threadIdx.x;
    const int m0 = blockIdx.x * BM;
    const int n0 = blockIdx.y * BM;
    const int lrow = tid >> 1;               // 0..127
    const int lkh  = (tid & 1) * 8;          // 0 or 8
    const int tx = tid & 15, ty = tid >> 4;

    float acc[2][2][4][4] = {};

    for (int k0 = 0; k0 < Ii; k0 += BK) {
        float4 a0 = *reinterpret_cast<const float4*>(&x[(size_t)(m0 + lrow) * Ii + k0 + lkh]);
        float4 a1 = *reinterpret_cast<const float4*>(&x[(size_t)(m0 + lrow) * Ii + k0 + lkh + 4]);
        float4 b0 = *reinterpret_cast<const float4*>(&Wx[(size_t)(n0 + lrow) * Ii + k0 + lkh]);
        float4 b1 = *reinterpret_cast<const float4*>(&Wx[(size_t)(n0 + lrow) * Ii + k0 + lkh + 4]);
        __syncthreads();
        As[lkh + 0][lrow] = a0.x; As[lkh + 1][lrow] = a0.y;
        As[lkh + 2][lrow] = a0.z; As[lkh + 3][lrow] = a0.w;
        As[lkh + 4][lrow] = a1.x; As[lkh + 5][lrow] = a1.y;
        As[lkh + 6][lrow] = a1.z; As[lkh + 7][lrow] = a1.w;
        Bs[lkh + 0][lrow] = b0.x; Bs[lkh + 1][lrow] = b0.y;
        Bs[lkh + 2][lrow] = b0.z; Bs[lkh + 3][lrow] = b0.w;
        Bs[lkh + 4][lrow] = b1.x; Bs[lkh + 5][lrow] = b1.y;
        Bs[lkh + 6][lrow] = b1.z; Bs[lkh + 7][lrow] = b1.w;
        __syncthreads();
        #pragma unroll
        for (int k = 0; k < BK; ++k) {
            float4 av[2], bv[2];
            av[0] = *reinterpret_cast<const float4*>(&As[k][ty * 4]);
            av[1] = *reinterpret_cast<const float4*>(&As[k][64 + ty * 4]);
            bv[0] = *reinterpret_cast<const float4*>(&Bs[k][tx * 4]);
            bv[1] = *reinterpret_cast<const float4*>(&Bs[k][64 + tx * 4]);
            #pragma unroll
            for (int rh = 0; rh < 2; ++rh) {
                const float* ap = reinterpret_cast<const float*>(&av[rh]);
                #pragma unroll
                for (int ch = 0; ch < 2; ++ch) {
                    const float* bp = reinterpret_cast<const float*>(&bv[ch]);
                    #pragma unroll
                    for (int i = 0; i < 4; ++i)
                        #pragma unroll
                        for (int j = 0; j < 4; ++j)
                            acc[rh][ch][i][j] += ap[i] * bp[j];
                }
            }
        }
    }

    float4 bias[2];
    #pragma unroll
    for (int ch = 0; ch < 2; ++ch) {
        int cb = n0 + ch * 64 + tx * 4;
        bias[ch] = make_float4(bx[cb] + bh[cb], bx[cb + 1] + bh[cb + 1],
                               bx[cb + 2] + bh[cb + 2], bx[cb + 3] + bh[cb + 3]);
    }
    #pragma unroll
    for (int rh = 0; rh < 2; ++rh)
        #pragma unroll
        for (int i = 0; i < 4; ++i) {
            size_t row = (size_t)(m0 + rh * 64 + ty * 4 + i);
            #pragma unroll
            for (int ch = 0; ch < 2; ++ch) {
                const float* bp = reinterpret_cast<const float*>(&bias[ch]);
                float4 v = make_float4(acc[rh][ch][i][0] + bp[0], acc[rh][ch][i][1] + bp[1],
                                       acc[rh][ch][i][2] + bp[2], acc[rh][ch][i][3] + bp[3]);
                *reinterpret_cast<float4*>(&xp[row * Hh + n0 + ch * 64 + tx * 4]) = v;
            }
        }
}

// ---------------- zero xbuf (every launch: tags per-launch monotonic) -------
__global__ void zero_xbuf(unsigned long long* __restrict__ xb)
{
    xb[(size_t)blockIdx.x * 512 + threadIdx.x] = 0ull;   // 64 blocks x 512
}

// ---------------- Phase 2: scan, 8 blocks/chain (R7 + staggered poll) -------
// bid: chain c = bid&31, part P = bid>>5. Wave w (0..7), lane=(hf,lp):
// thread rows P*64 + w*8 + hf*4 + s (s=0..3), cols q*128 + lp*4 + i.
// Wave P = finisher (reduce+tanh+publish); waves w!=P poll part w's
// {tag,val} qwords with a 3-deep staggered rotating poll.
__global__ __launch_bounds__(512, 1)
void rnn_scan_mb(const float* __restrict__ Wh, const float* __restrict__ h0,
                 float* __restrict__ out, unsigned long long* __restrict__ xbuf)
{
    const int bid = blockIdx.x;
    const int c = bid & 31;
    const int P = bid >> 5;
    const int tid = threadIdx.x;
    const int w = tid >> 6;          // wave 0..7
    const int lane = tid & 63;
    const int hf = lane >> 5, lp = lane & 31;
    const int lrow0 = w * 8 + hf * 4;          // local row base 0..60

    __shared__ __align__(16) float hs[Hh];
    __shared__ __align__(16) float pq[32][68];     // [lp][row] transposed partials

    // ---- weights -> registers via opaque asm loads (no remat possible) ----
    float4 wreg[4][4];
    #pragma unroll
    for (int s = 0; s < 4; ++s)
        #pragma unroll
        for (int q = 0; q < 4; ++q) {
            const float* ap = &Wh[(size_t)(P * RP + lrow0 + s) * Hh + q * 128 + lp * 4];
            asm volatile("global_load_dwordx4 %0, %1, off"
                         : "=v"(wreg[s][q]) : "v"(ap));
        }
    asm volatile("s_waitcnt vmcnt(0)" ::: "memory");

    hs[tid] = h0[(size_t)c * Hh + tid];

    float* ob = out + (size_t)c * Tt * Hh;                // xp -> h in place
    unsigned long long* xb = xbuf + (size_t)c * 2 * Hh;   // [slot][row]

    const bool isFin = (w == P);
    float xp_cur = 0.f;
    if (isFin) xp_cur = ob[P * RP + lane];                // finisher: xp row t=0
    __syncthreads();                                      // hs = h0 ready

    for (int t = 0; t < Tt; ++t) {
        const int d = t & 1;
        const bool cons = (!isFin) && (t + 1 < Tt);
        const unsigned long long* pa = &xb[(size_t)d * Hh + w * RP + lane];
        unsigned long long mA = 0, mB = 0, mC = 0;

        // ---- h fragments (LDS, issued up front)
        float4 hv0 = *reinterpret_cast<const float4*>(&hs[0 * 128 + lp * 4]);
        float4 hv1 = *reinterpret_cast<const float4*>(&hs[1 * 128 + lp * 4]);
        float4 hv2 = *reinterpret_cast<const float4*>(&hs[2 * 128 + lp * 4]);
        float4 hv3 = *reinterpret_cast<const float4*>(&hs[3 * 128 + lp * 4]);

        // ---- poll issue #1 (in flight during FMA chunk 1)
        if (cons) mA = __hip_atomic_load(pa, __ATOMIC_RELAXED, __HIP_MEMORY_SCOPE_AGENT);
        asm volatile("" ::: "memory");

        // ---- FMA chunk 1: q = 0,1
        float a0 = 0.f, a1 = 0.f, a2 = 0.f, a3 = 0.f;
        {
            const float* h0p = reinterpret_cast<const float*>(&hv0);
            const float* h1p = reinterpret_cast<const float*>(&hv1);
            #pragma unroll
            for (int i = 0; i < 4; ++i) {
                a0 += reinterpret_cast<const float*>(&wreg[0][0])[i] * h0p[i];
                a1 += reinterpret_cast<const float*>(&wreg[1][0])[i] * h0p[i];
                a2 += reinterpret_cast<const float*>(&wreg[2][0])[i] * h0p[i];
                a3 += reinterpret_cast<const float*>(&wreg[3][0])[i] * h0p[i];
            }
            #pragma unroll
            for (int i = 0; i < 4; ++i) {
                a0 += reinterpret_cast<const float*>(&wreg[0][1])[i] * h1p[i];
                a1 += reinterpret_cast<const float*>(&wreg[1][1])[i] * h1p[i];
                a2 += reinterpret_cast<const float*>(&wreg[2][1])[i] * h1p[i];
                a3 += reinterpret_cast<const float*>(&wreg[3][1])[i] * h1p[i];
            }
        }

        // ---- poll issue #2
        if (cons) mB = __hip_atomic_load(pa, __ATOMIC_RELAXED, __HIP_MEMORY_SCOPE_AGENT);
        asm volatile("" ::: "memory");

        // ---- FMA chunk 2: q = 2,3
        {
            const float* h2p = reinterpret_cast<const float*>(&hv2);
            const float* h3p = reinterpret_cast<const float*>(&hv3);
            #pragma unroll
            for (int i = 0; i < 4; ++i) {
                a0 += reinterpret_cast<const float*>(&wreg[0][2])[i] * h2p[i];
                a1 += reinterpret_cast<const float*>(&wreg[1][2])[i] * h2p[i];
                a2 += reinterpret_cast<const float*>(&wreg[2][2])[i] * h2p[i];
                a3 += reinterpret_cast<const float*>(&wreg[3][2])[i] * h2p[i];
            }
            #pragma unroll
            for (int i = 0; i < 4; ++i) {
                a0 += reinterpret_cast<const float*>(&wreg[0][3])[i] * h3p[i];
                a1 += reinterpret_cast<const float*>(&wreg[1][3])[i] * h3p[i];
                a2 += reinterpret_cast<const float*>(&wreg[2][3])[i] * h3p[i];
                a3 += reinterpret_cast<const float*>(&wreg[3][3])[i] * h3p[i];
            }
        }

        // ---- poll issue #3
        if (cons) mC = __hip_atomic_load(pa, __ATOMIC_RELAXED, __HIP_MEMORY_SCOPE_AGENT);
        asm volatile("" ::: "memory");

        // ---- partials: transposed, conflict-aware b128 write
        *reinterpret_cast<float4*>(&pq[lp][lrow0]) = make_float4(a0, a1, a2, a3);
        __syncthreads();                 // B-mid: pq ready; hs reads done

        if (isFin) {
            // ---- finisher: row = P*64 + lane; conflict-free b32 column reads
            float s0 = xp_cur, s1 = 0.f, s2 = 0.f, s3 = 0.f;
            #pragma unroll
            for (int g = 0; g < 32; g += 4) {
                s0 += pq[g + 0][lane];
                s1 += pq[g + 1][lane];
                s2 += pq[g + 2][lane];
                s3 += pq[g + 3][lane];
            }
            float hval = fast_tanh((s0 + s1) + (s2 + s3));
            if (t + 1 < Tt) {
                unsigned long long msg =
                    ((unsigned long long)(unsigned)(t + 1) << 32) |
                    (unsigned long long)__float_as_uint(hval);
                __hip_atomic_store(&xb[(size_t)d * Hh + P * RP + lane], msg,
                                   __ATOMIC_RELAXED, __HIP_MEMORY_SCOPE_AGENT);
                ob[(size_t)t * Hh + P * RP + lane] = hval;
                hs[P * RP + lane] = hval;
                xp_cur = ob[(size_t)(t + 1) * Hh + P * RP + lane];   // prefetch
            } else {
                ob[(size_t)t * Hh + P * RP + lane] = hval;
                out[(size_t)Bb * Tt * Hh + (size_t)c * Hh + P * RP + lane] = hval;
            }
        } else if (cons) {
            // ---- rotating check + reissue (self-clocking ~lat/3 cadence)
            const unsigned want = (unsigned)(t + 1);
            unsigned val;
            for (;;) {
                if ((unsigned)(mA >> 32) == want) { val = (unsigned)mA; break; }
                mA = __hip_atomic_load(pa, __ATOMIC_RELAXED, __HIP_MEMORY_SCOPE_AGENT);
                if ((unsigned)(mB >> 32) == want) { val = (unsigned)mB; break; }
                mB = __hip_atomic_load(pa, __ATOMIC_RELAXED, __HIP_MEMORY_SCOPE_AGENT);
                if ((unsigned)(mC >> 32) == want) { val = (unsigned)mC; break; }
                mC = __hip_atomic_load(pa, __ATOMIC_RELAXED, __HIP_MEMORY_SCOPE_AGENT);
            }
            hs[w * RP + lane] = __uint_as_float(val);
        }
        __syncthreads();                 // B-end: hs = h(t) complete
    }
}

// ---------------- Fallback single-block scan (tiny ws) ----------------
__global__ __launch_bounds__(512)
void rnn_scan_sb(const float* __restrict__ W, const float* __restrict__ h0,
                 float* __restrict__ out)
{
    const int b = blockIdx.x;
    const int j = threadIdx.x;
    __shared__ float hsb[2][Hh];
    hsb[0][j] = h0[(size_t)b * Hh + j];
    __syncthreads();

    float* ob = out + (size_t)b * Tt * Hh;
    const float* wbase = W + (size_t)j * Hh;

    float xp_cur = ob[j];
    int cur = 0;
    for (int t = 0; t < Tt; ++t) {
        float xp_next = (t + 1 < Tt) ? ob[(size_t)(t + 1) * Hh + j] : 0.0f;
        float4 a = make_float4(xp_cur, 0.0f, 0.0f, 0.0f);
        const float* h = hsb[cur];
        #pragma unroll 8
        for (int c4 = 0; c4 < Hh / 4; ++c4) {
            float4 wv = *reinterpret_cast<const float4*>(&wbase[c4 * 4]);
            float4 hv = *reinterpret_cast<const float4*>(&h[c4 * 4]);
            a.x += wv.x * hv.x; a.y += wv.y * hv.y;
            a.z += wv.z * hv.z; a.w += wv.w * hv.w;
        }
        float hn = tanhf((a.x + a.y) + (a.z + a.w));
        hsb[cur ^ 1][j] = hn;
        ob[(size_t)t * Hh + j] = hn;
        xp_cur = xp_next;
        cur ^= 1;
        __syncthreads();
    }
    out[(size_t)Bb * Tt * Hh + (size_t)b * Hh + j] = hsb[cur][j];
}

extern "C" void kernel_launch(void* const* d_in, const int* in_sizes, int n_in,
                              void* d_out, int out_size, void* d_ws, size_t ws_size,
                              hipStream_t stream)
{
    const float* x  = (const float*)d_in[0];
    const float* h0 = (const float*)d_in[1];
    const float* Wx = (const float*)d_in[2];
    const float* bx = (const float*)d_in[3];
    const float* Wh = (const float*)d_in[4];
    const float* bh = (const float*)d_in[5];
    float* out = (float*)d_out;

    dim3 g1(Bb * Tt / 128, Hh / 128);     // (512, 4)
    xproj_gemm<<<g1, 256, 0, stream>>>(x, Wx, bx, bh, out);

    const size_t xb_bytes = (size_t)Bb * 2 * Hh * sizeof(unsigned long long); // 256 KB
    if (ws_size >= xb_bytes) {
        unsigned long long* xbuf = (unsigned long long*)d_ws;
        zero_xbuf<<<64, 512, 0, stream>>>(xbuf);
        void* args[] = {(void*)&Wh, (void*)&h0, (void*)&out, (void*)&xbuf};
        hipLaunchCooperativeKernel((void*)rnn_scan_mb, dim3(NP * Bb), dim3(512),
                                   args, 0, stream);
    } else {
        rnn_scan_sb<<<Bb, Hh, 0, stream>>>(Wh, h0, out);
    }
}